// Round 1
// baseline (191.041 us; speedup 1.0000x reference)
//
#include <hip/hip_runtime.h>

#define QMAX 127.0f
#define BM 128
#define BN 128
#define BK 64

typedef int int4v __attribute__((ext_vector_type(4)));

// ---------------- init: zero the two absmax slots (ws is poisoned 0xAA) ----
__global__ void init_kernel(unsigned* amax) {
    if (threadIdx.x < 2) amax[threadIdx.x] = 0u;
}

// ---------------- absmax reduction (float bits compare as uint for >=0) ----
__global__ void absmax_kernel(const float4* __restrict__ p, int n4, unsigned* out) {
    float m = 0.f;
    int stride = gridDim.x * blockDim.x;
    for (int i = blockIdx.x * blockDim.x + threadIdx.x; i < n4; i += stride) {
        float4 v = p[i];
        m = fmaxf(m, fmaxf(fmaxf(fabsf(v.x), fabsf(v.y)),
                           fmaxf(fabsf(v.z), fabsf(v.w))));
    }
    for (int off = 32; off; off >>= 1) m = fmaxf(m, __shfl_down(m, off, 64));
    __shared__ float sm[4];
    if ((threadIdx.x & 63) == 0) sm[threadIdx.x >> 6] = m;
    __syncthreads();
    if (threadIdx.x == 0) {
        float b = fmaxf(fmaxf(sm[0], sm[1]), fmaxf(sm[2], sm[3]));
        atomicMax(out, __float_as_uint(b));
    }
}

// ---------------- quantize: q = clamp(round_ne(v / scale), -127, 127) ------
__device__ __forceinline__ int qone(float v, float s) {
    float q = fminf(fmaxf(rintf(v / s), -QMAX), QMAX);
    return (int)q;
}
__device__ __forceinline__ int qpack4(float4 v, float s) {
    return (qone(v.x, s) & 255) | ((qone(v.y, s) & 255) << 8) |
           ((qone(v.z, s) & 255) << 16) | ((qone(v.w, s) & 255) << 24);
}

__global__ void quant_kernel(const float4* __restrict__ src, int4v* __restrict__ dst,
                             int n16, const unsigned* __restrict__ amax) {
    float scale = __uint_as_float(*amax) / QMAX;  // matches reference: max/127
    int stride = gridDim.x * blockDim.x;
    for (int i = blockIdx.x * blockDim.x + threadIdx.x; i < n16; i += stride) {
        float4 v0 = src[4 * i + 0];
        float4 v1 = src[4 * i + 1];
        float4 v2 = src[4 * i + 2];
        float4 v3 = src[4 * i + 3];
        int4v o = { qpack4(v0, scale), qpack4(v1, scale),
                    qpack4(v2, scale), qpack4(v3, scale) };
        dst[i] = o;
    }
}

// ---------------- int8 GEMM: acc[m,n] = sum_k qx[m,k]*qw[n,k] --------------
typedef const __attribute__((address_space(1))) char glob_char;
typedef __attribute__((address_space(3))) char lds_char;

__device__ __forceinline__ void gload16(const char* g, char* l) {
    __builtin_amdgcn_global_load_lds((glob_char*)g, (lds_char*)l, 16, 0, 0);
}

// LDS layout (fragment order): slot(g, q, r) = g*64 + q*16 + r   (16B chunks)
//   g = 16-row group (0..7), r = row within group (0..15), q = 16-byte k-chunk (0..3)
// Frag read for m-tile g: lane L reads slot g*64 + L  -> lane-sequential, conflict-free.
// Staging: linear LDS index L = c*256 + tid maps to row = (L>>6)*16 + (L&15),
//          col = ((L>>4)&3)*16 -- satisfies global_load_lds lane-linear LDS rule.
__global__ __launch_bounds__(256, 2) void gemm_i8_kernel(
        const char* __restrict__ qa, const char* __restrict__ qb,
        const float* __restrict__ bias, const unsigned* __restrict__ amax,
        float* __restrict__ out, int M, int N, int K) {
    __shared__ char sA[BM * BK];
    __shared__ char sB[BN * BK];

    const int tid = threadIdx.x;
    const int lane = tid & 63;
    const int wid = tid >> 6;
    const int wm = wid >> 1, wn = wid & 1;
    const int m0 = blockIdx.y * BM, n0 = blockIdx.x * BN;

    const int L0 = tid, L1 = 256 + tid;
    const int row0 = ((L0 >> 6) << 4) + (L0 & 15);
    const int col0 = ((L0 >> 4) & 3) << 4;
    const int row1 = ((L1 >> 6) << 4) + (L1 & 15);
    const int col1 = ((L1 >> 4) & 3) << 4;

    const char* gA0 = qa + (size_t)(m0 + row0) * K + col0;
    const char* gA1 = qa + (size_t)(m0 + row1) * K + col1;
    const char* gB0 = qb + (size_t)(n0 + row0) * K + col0;
    const char* gB1 = qb + (size_t)(n0 + row1) * K + col1;
    char* lA0 = sA + L0 * 16;
    char* lA1 = sA + L1 * 16;
    char* lB0 = sB + L0 * 16;
    char* lB1 = sB + L1 * 16;

    int4v acc[4][4];
    const int4v zero = {0, 0, 0, 0};
#pragma unroll
    for (int i = 0; i < 4; ++i)
#pragma unroll
        for (int j = 0; j < 4; ++j) acc[i][j] = zero;

    const int4v* sAv = (const int4v*)sA;
    const int4v* sBv = (const int4v*)sB;
    const int aoff = wm * 4 * 64 + lane;  // + mt*64
    const int boff = wn * 4 * 64 + lane;  // + nt*64

    for (int k0 = 0; k0 < K; k0 += BK) {
        gload16(gA0, lA0);
        gload16(gA1, lA1);
        gload16(gB0, lB0);
        gload16(gB1, lB1);
        gA0 += BK; gA1 += BK; gB0 += BK; gB1 += BK;
        __syncthreads();  // compiler drains vmcnt here (global_load_lds done)

        int4v a[4], b[4];
#pragma unroll
        for (int t = 0; t < 4; ++t) {
            a[t] = sAv[aoff + t * 64];
            b[t] = sBv[boff + t * 64];
        }
#pragma unroll
        for (int i = 0; i < 4; ++i)
#pragma unroll
            for (int j = 0; j < 4; ++j)
                acc[i][j] = __builtin_amdgcn_mfma_i32_16x16x64_i8(a[i], b[j], acc[i][j], 0, 0, 0);
        __syncthreads();  // all waves done reading LDS before next stage
    }

    // dequant + bias.  C/D layout (16x16): col = lane&15, row = (lane>>4)*4 + reg
    const float s = (__uint_as_float(amax[0]) / QMAX) * (__uint_as_float(amax[1]) / QMAX);
    const int cbase = n0 + wn * 64 + (lane & 15);
    const int rbase = m0 + wm * 64 + ((lane >> 4) << 2);
#pragma unroll
    for (int j = 0; j < 4; ++j) {
        const int col = cbase + j * 16;
        const float bv = bias[col];
#pragma unroll
        for (int i = 0; i < 4; ++i) {
            const int row = rbase + i * 16;
#pragma unroll
            for (int r = 0; r < 4; ++r) {
                out[(size_t)(row + r) * N + col] = (float)acc[i][j][r] * s + bv;
            }
        }
    }
}

extern "C" void kernel_launch(void* const* d_in, const int* in_sizes, int n_in,
                              void* d_out, int out_size, void* d_ws, size_t ws_size,
                              hipStream_t stream) {
    const float* x = (const float*)d_in[0];     // [M, K]
    const float* w = (const float*)d_in[1];     // [N, K] (row-major = B^T)
    const float* bias = (const float*)d_in[2];  // [N]
    float* out = (float*)d_out;

    const int xn = in_sizes[0];
    const int wn = in_sizes[1];
    const int N = in_sizes[2];
    const int K = wn / N;
    const int M = xn / K;

    unsigned* amax = (unsigned*)d_ws;           // [0]=absmax(x) bits, [1]=absmax(w) bits
    char* qx = (char*)d_ws + 1024;
    char* qw = qx + (size_t)M * K;

    init_kernel<<<1, 64, 0, stream>>>(amax);
    absmax_kernel<<<2048, 256, 0, stream>>>((const float4*)x, xn / 4, amax + 0);
    absmax_kernel<<<256, 256, 0, stream>>>((const float4*)w, wn / 4, amax + 1);
    quant_kernel<<<4096, 256, 0, stream>>>((const float4*)x, (int4v*)qx, xn / 16, amax + 0);
    quant_kernel<<<256, 256, 0, stream>>>((const float4*)w, (int4v*)qw, wn / 16, amax + 1);
    gemm_i8_kernel<<<dim3(N / BN, M / BM), 256, 0, stream>>>(qx, qw, bias, amax, out, M, N, K);
}

// Round 2
// 181.483 us; speedup vs baseline: 1.0527x; 1.0527x over previous
//
#include <hip/hip_runtime.h>

#define QMAX 127.0f
#define BM 128
#define BN 128
#define BK 64

typedef int int4v __attribute__((ext_vector_type(4)));

// ---------------- fused absmax for x and w -------------------------------
// No init needed: ws poison 0xAAAAAAAA is negative as signed int; abs-float
// bit patterns are non-negative ints, so atomicMax(int*) recovers the max.
__global__ void absmax2_kernel(const float4* __restrict__ px, int n4x,
                               const float4* __restrict__ pw, int n4w,
                               int gx, int* __restrict__ amax) {
    const float4* p; int n4; int* out; int nb, bid;
    if ((int)blockIdx.x < gx) { p = px; n4 = n4x; out = amax + 0; nb = gx; bid = blockIdx.x; }
    else { p = pw; n4 = n4w; out = amax + 1; nb = gridDim.x - gx; bid = blockIdx.x - gx; }
    float m = 0.f;
    int stride = nb * blockDim.x;
    for (int i = bid * blockDim.x + threadIdx.x; i < n4; i += stride) {
        float4 v = p[i];
        m = fmaxf(m, fmaxf(fmaxf(fabsf(v.x), fabsf(v.y)),
                           fmaxf(fabsf(v.z), fabsf(v.w))));
    }
    for (int off = 32; off; off >>= 1) m = fmaxf(m, __shfl_down(m, off, 64));
    __shared__ float sm[4];
    if ((threadIdx.x & 63) == 0) sm[threadIdx.x >> 6] = m;
    __syncthreads();
    if (threadIdx.x == 0) {
        float b = fmaxf(fmaxf(sm[0], sm[1]), fmaxf(sm[2], sm[3]));
        atomicMax(out, (int)__float_as_uint(b));
    }
}

// ---------------- fused quantize x and w ---------------------------------
__device__ __forceinline__ int qone(float v, float s) {
    float q = fminf(fmaxf(rintf(v / s), -QMAX), QMAX);
    return (int)q;
}
__device__ __forceinline__ int qpack4(float4 v, float s) {
    return (qone(v.x, s) & 255) | ((qone(v.y, s) & 255) << 8) |
           ((qone(v.z, s) & 255) << 16) | ((qone(v.w, s) & 255) << 24);
}

__global__ void quant2_kernel(const float4* __restrict__ sx, int4v* __restrict__ dx, int n16x,
                              const float4* __restrict__ sw, int4v* __restrict__ dw, int n16w,
                              int gx, const int* __restrict__ amax) {
    const float4* src; int4v* dst; int n16, nb, bid; float scale;
    if ((int)blockIdx.x < gx) {
        src = sx; dst = dx; n16 = n16x; nb = gx; bid = blockIdx.x;
        scale = __uint_as_float((unsigned)amax[0]) / QMAX;
    } else {
        src = sw; dst = dw; n16 = n16w; nb = gridDim.x - gx; bid = blockIdx.x - gx;
        scale = __uint_as_float((unsigned)amax[1]) / QMAX;
    }
    int stride = nb * blockDim.x;
    for (int i = bid * blockDim.x + threadIdx.x; i < n16; i += stride) {
        float4 v0 = src[4 * i + 0];
        float4 v1 = src[4 * i + 1];
        float4 v2 = src[4 * i + 2];
        float4 v3 = src[4 * i + 3];
        int4v o = { qpack4(v0, scale), qpack4(v1, scale),
                    qpack4(v2, scale), qpack4(v3, scale) };
        dst[i] = o;
    }
}

// ---------------- int8 GEMM: acc[m,n] = sum_k qx[m,k]*qw[n,k] --------------
typedef const __attribute__((address_space(1))) char glob_char;
typedef __attribute__((address_space(3))) char lds_char;

__device__ __forceinline__ void gload16(const char* g, char* l) {
    __builtin_amdgcn_global_load_lds((glob_char*)g, (lds_char*)l, 16, 0, 0);
}

// LDS layout (fragment order): slot(g, q, r) = g*64 + q*16 + r   (16B chunks)
// Frag read for tile g: lane L reads slot g*64 + L -> lane-sequential, no conflicts.
// Staging satisfies global_load_lds's wave-uniform-base + lane*16 rule.
__global__ __launch_bounds__(256, 4) void gemm_i8_kernel(
        const char* __restrict__ qa, const char* __restrict__ qb,
        const float* __restrict__ bias, const int* __restrict__ amax,
        float* __restrict__ out, int M, int N, int K, int nbx) {
    __shared__ char sA[BM * BK];
    __shared__ char sB[BN * BK];

    // XCD swizzle: round-robin b%8 -> XCD; give each XCD a contiguous chunk of
    // s so its 4MB L2 sees 16 m-strips x all n-tiles (2MB qx + 1MB qw working set).
    const int b = blockIdx.x;
    const int chunk = gridDim.x >> 3;
    const int s = (b & 7) * chunk + (b >> 3);
    const int mt = s / nbx, nt = s % nbx;

    const int tid = threadIdx.x;
    const int lane = tid & 63;
    const int wid = tid >> 6;
    const int wm = wid >> 1, wn = wid & 1;
    const int m0 = mt * BM, n0 = nt * BN;

    const int L0 = tid, L1 = 256 + tid;
    const int row0 = ((L0 >> 6) << 4) + (L0 & 15);
    const int col0 = ((L0 >> 4) & 3) << 4;
    const int row1 = ((L1 >> 6) << 4) + (L1 & 15);
    const int col1 = ((L1 >> 4) & 3) << 4;

    const char* gA0 = qa + (size_t)(m0 + row0) * K + col0;
    const char* gA1 = qa + (size_t)(m0 + row1) * K + col1;
    const char* gB0 = qb + (size_t)(n0 + row0) * K + col0;
    const char* gB1 = qb + (size_t)(n0 + row1) * K + col1;
    char* lA0 = sA + L0 * 16;
    char* lA1 = sA + L1 * 16;
    char* lB0 = sB + L0 * 16;
    char* lB1 = sB + L1 * 16;

    int4v acc[4][4];
    const int4v zero = {0, 0, 0, 0};
#pragma unroll
    for (int i = 0; i < 4; ++i)
#pragma unroll
        for (int j = 0; j < 4; ++j) acc[i][j] = zero;

    const int4v* sAv = (const int4v*)sA;
    const int4v* sBv = (const int4v*)sB;
    const int aoff = wm * 4 * 64 + lane;
    const int boff = wn * 4 * 64 + lane;

    for (int k0 = 0; k0 < K; k0 += BK) {
        gload16(gA0, lA0);
        gload16(gA1, lA1);
        gload16(gB0, lB0);
        gload16(gB1, lB1);
        gA0 += BK; gA1 += BK; gB0 += BK; gB1 += BK;
        __syncthreads();

        int4v a[4], bfr[4];
#pragma unroll
        for (int t = 0; t < 4; ++t) {
            a[t] = sAv[aoff + t * 64];
            bfr[t] = sBv[boff + t * 64];
        }
#pragma unroll
        for (int i = 0; i < 4; ++i)
#pragma unroll
            for (int j = 0; j < 4; ++j)
                acc[i][j] = __builtin_amdgcn_mfma_i32_16x16x64_i8(a[i], bfr[j], acc[i][j], 0, 0, 0);
        __syncthreads();
    }

    // dequant + bias.  C/D layout (16x16): col = lane&15, row = (lane>>4)*4 + reg
    const float sc = (__uint_as_float((unsigned)amax[0]) / QMAX) *
                     (__uint_as_float((unsigned)amax[1]) / QMAX);
    const int cbase = n0 + wn * 64 + (lane & 15);
    const int rbase = m0 + wm * 64 + ((lane >> 4) << 2);
#pragma unroll
    for (int j = 0; j < 4; ++j) {
        const int col = cbase + j * 16;
        const float bv = bias[col];
#pragma unroll
        for (int i = 0; i < 4; ++i) {
            const int row = rbase + i * 16;
#pragma unroll
            for (int r = 0; r < 4; ++r) {
                out[(size_t)(row + r) * N + col] = (float)acc[i][j][r] * sc + bv;
            }
        }
    }
}

extern "C" void kernel_launch(void* const* d_in, const int* in_sizes, int n_in,
                              void* d_out, int out_size, void* d_ws, size_t ws_size,
                              hipStream_t stream) {
    const float* x = (const float*)d_in[0];     // [M, K]
    const float* w = (const float*)d_in[1];     // [N, K] (row-major = B^T)
    const float* bias = (const float*)d_in[2];  // [N]
    float* out = (float*)d_out;

    const int xn = in_sizes[0];
    const int wn = in_sizes[1];
    const int N = in_sizes[2];
    const int K = wn / N;
    const int M = xn / K;

    int* amax = (int*)d_ws;                     // [0]=absmax(x) bits, [1]=absmax(w) bits
    char* qx = (char*)d_ws + 1024;
    char* qw = qx + (size_t)M * K;

    const int GAX = 2048, GAW = 256;
    absmax2_kernel<<<GAX + GAW, 256, 0, stream>>>(
        (const float4*)x, xn / 4, (const float4*)w, wn / 4, GAX, amax);

    const int GQX = 4096, GQW = 256;
    quant2_kernel<<<GQX + GQW, 256, 0, stream>>>(
        (const float4*)x, (int4v*)qx, xn / 16,
        (const float4*)w, (int4v*)qw, wn / 16, GQX, amax);

    const int nbx = N / BN;
    gemm_i8_kernel<<<nbx * (M / BM), 256, 0, stream>>>(qx, qw, bias, amax, out, M, N, K, nbx);
}

// Round 3
// 181.212 us; speedup vs baseline: 1.0542x; 1.0015x over previous
//
#include <hip/hip_runtime.h>

#define QMAX 127.0f
#define BM 128
#define BN 128
#define BK 64

typedef int int4v __attribute__((ext_vector_type(4)));

// ---------------- fused absmax for x and w -------------------------------
// No init needed: ws poison 0xAAAAAAAA is negative as signed int; abs-float
// bit patterns are non-negative ints, so atomicMax(int*) recovers the max.
__global__ void absmax2_kernel(const float4* __restrict__ px, int n4x,
                               const float4* __restrict__ pw, int n4w,
                               int gx, int* __restrict__ amax) {
    const float4* p; int n4; int* out; int nb, bid;
    if ((int)blockIdx.x < gx) { p = px; n4 = n4x; out = amax + 0; nb = gx; bid = blockIdx.x; }
    else { p = pw; n4 = n4w; out = amax + 1; nb = gridDim.x - gx; bid = blockIdx.x - gx; }
    float m = 0.f;
    int stride = nb * blockDim.x;
    for (int i = bid * blockDim.x + threadIdx.x; i < n4; i += stride) {
        float4 v = p[i];
        m = fmaxf(m, fmaxf(fmaxf(fabsf(v.x), fabsf(v.y)),
                           fmaxf(fabsf(v.z), fabsf(v.w))));
    }
    for (int off = 32; off; off >>= 1) m = fmaxf(m, __shfl_down(m, off, 64));
    __shared__ float sm[4];
    if ((threadIdx.x & 63) == 0) sm[threadIdx.x >> 6] = m;
    __syncthreads();
    if (threadIdx.x == 0) {
        float b = fmaxf(fmaxf(sm[0], sm[1]), fmaxf(sm[2], sm[3]));
        atomicMax(out, (int)__float_as_uint(b));
    }
}

// ---------------- fused quantize x and w ---------------------------------
__device__ __forceinline__ int qone(float v, float s) {
    float q = fminf(fmaxf(rintf(v / s), -QMAX), QMAX);
    return (int)q;
}
__device__ __forceinline__ int qpack4(float4 v, float s) {
    return (qone(v.x, s) & 255) | ((qone(v.y, s) & 255) << 8) |
           ((qone(v.z, s) & 255) << 16) | ((qone(v.w, s) & 255) << 24);
}

__global__ void quant2_kernel(const float4* __restrict__ sx, int4v* __restrict__ dx, int n16x,
                              const float4* __restrict__ sw, int4v* __restrict__ dw, int n16w,
                              int gx, const int* __restrict__ amax) {
    const float4* src; int4v* dst; int n16, nb, bid; float scale;
    if ((int)blockIdx.x < gx) {
        src = sx; dst = dx; n16 = n16x; nb = gx; bid = blockIdx.x;
        scale = __uint_as_float((unsigned)amax[0]) / QMAX;
    } else {
        src = sw; dst = dw; n16 = n16w; nb = gridDim.x - gx; bid = blockIdx.x - gx;
        scale = __uint_as_float((unsigned)amax[1]) / QMAX;
    }
    int stride = nb * blockDim.x;
    for (int i = bid * blockDim.x + threadIdx.x; i < n16; i += stride) {
        float4 v0 = src[4 * i + 0];
        float4 v1 = src[4 * i + 1];
        float4 v2 = src[4 * i + 2];
        float4 v3 = src[4 * i + 3];
        int4v o = { qpack4(v0, scale), qpack4(v1, scale),
                    qpack4(v2, scale), qpack4(v3, scale) };
        dst[i] = o;
    }
}

// ---------------- int8 GEMM: acc[m,n] = sum_k qx[m,k]*qw[n,k] --------------
typedef const __attribute__((address_space(1))) char glob_char;
typedef __attribute__((address_space(3))) char lds_char;

__device__ __forceinline__ void gload16(const char* g, char* l) {
    __builtin_amdgcn_global_load_lds((glob_char*)g, (lds_char*)l, 16, 0, 0);
}

// LDS layout (fragment order): slot(g, q, r) = g*64 + q*16 + r   (16B chunks)
// Frag read for tile g: lane L reads slot g*64 + L -> lane-sequential, no conflicts.
// Staging satisfies global_load_lds's wave-uniform-base + lane*16 rule.
//
// K-loop is double-buffered with prefetch-after-barrier: the barrier's
// vmcnt(0) drain waits on loads issued one full compute phase earlier,
// hiding the global->LDS latency that made the single-buffer version
// latency-bound (45 us vs ~12 us resource bound).
__global__ __launch_bounds__(256, 4) void gemm_i8_kernel(
        const char* __restrict__ qa, const char* __restrict__ qb,
        const float* __restrict__ bias, const int* __restrict__ amax,
        float* __restrict__ out, int M, int N, int K, int nbx) {
    __shared__ char sA[2][BM * BK];
    __shared__ char sB[2][BN * BK];

    // XCD swizzle: round-robin b%8 -> XCD; contiguous chunk of tile-space per
    // XCD so its 4MB L2 holds the working set (2MB qx strip + 1MB qw).
    const int b = blockIdx.x;
    const int chunk = gridDim.x >> 3;
    const int s = (b & 7) * chunk + (b >> 3);
    const int mt = s / nbx, nt = s % nbx;

    const int tid = threadIdx.x;
    const int lane = tid & 63;
    const int wid = tid >> 6;
    const int wm = wid >> 1, wn = wid & 1;
    const int m0 = mt * BM, n0 = nt * BN;

    const int L0 = tid, L1 = 256 + tid;
    const int row0 = ((L0 >> 6) << 4) + (L0 & 15);
    const int col0 = ((L0 >> 4) & 3) << 4;
    const int row1 = ((L1 >> 6) << 4) + (L1 & 15);
    const int col1 = ((L1 >> 4) & 3) << 4;

    const char* gA0 = qa + (size_t)(m0 + row0) * K + col0;
    const char* gA1 = qa + (size_t)(m0 + row1) * K + col1;
    const char* gB0 = qb + (size_t)(n0 + row0) * K + col0;
    const char* gB1 = qb + (size_t)(n0 + row1) * K + col1;

    int4v acc[4][4];
    const int4v zero = {0, 0, 0, 0};
#pragma unroll
    for (int i = 0; i < 4; ++i)
#pragma unroll
        for (int j = 0; j < 4; ++j) acc[i][j] = zero;

    const int aoff = wm * 4 * 64 + lane;
    const int boff = wn * 4 * 64 + lane;
    const int NI = K / BK;

    // prologue: stage tile 0 into buffer 0
    gload16(gA0, sA[0] + L0 * 16);
    gload16(gA1, sA[0] + L1 * 16);
    gload16(gB0, sB[0] + L0 * 16);
    gload16(gB1, sB[0] + L1 * 16);
    gA0 += BK; gA1 += BK; gB0 += BK; gB1 += BK;

    for (int k0 = 0; k0 < NI; ++k0) {
        const int cur = k0 & 1;
        __syncthreads();  // drains stage(k0) vmcnt + prior iter's ds_reads

        if (k0 + 1 < NI) {  // prefetch tile k0+1 into the other buffer
            const int nxt = cur ^ 1;
            gload16(gA0, sA[nxt] + L0 * 16);
            gload16(gA1, sA[nxt] + L1 * 16);
            gload16(gB0, sB[nxt] + L0 * 16);
            gload16(gB1, sB[nxt] + L1 * 16);
            gA0 += BK; gA1 += BK; gB0 += BK; gB1 += BK;
        }

        const int4v* sAv = (const int4v*)sA[cur];
        const int4v* sBv = (const int4v*)sB[cur];
        int4v a[4], bfr[4];
#pragma unroll
        for (int t = 0; t < 4; ++t) {
            a[t] = sAv[aoff + t * 64];
            bfr[t] = sBv[boff + t * 64];
        }
#pragma unroll
        for (int i = 0; i < 4; ++i)
#pragma unroll
            for (int j = 0; j < 4; ++j)
                acc[i][j] = __builtin_amdgcn_mfma_i32_16x16x64_i8(a[i], bfr[j], acc[i][j], 0, 0, 0);
    }

    // dequant + bias.  C/D layout (16x16): col = lane&15, row = (lane>>4)*4 + reg
    const float sc = (__uint_as_float((unsigned)amax[0]) / QMAX) *
                     (__uint_as_float((unsigned)amax[1]) / QMAX);
    const int cbase = n0 + wn * 64 + (lane & 15);
    const int rbase = m0 + wm * 64 + ((lane >> 4) << 2);
#pragma unroll
    for (int j = 0; j < 4; ++j) {
        const int col = cbase + j * 16;
        const float bv = bias[col];
#pragma unroll
        for (int i = 0; i < 4; ++i) {
            const int row = rbase + i * 16;
#pragma unroll
            for (int r = 0; r < 4; ++r) {
                out[(size_t)(row + r) * N + col] = (float)acc[i][j][r] * sc + bv;
            }
        }
    }
}

extern "C" void kernel_launch(void* const* d_in, const int* in_sizes, int n_in,
                              void* d_out, int out_size, void* d_ws, size_t ws_size,
                              hipStream_t stream) {
    const float* x = (const float*)d_in[0];     // [M, K]
    const float* w = (const float*)d_in[1];     // [N, K] (row-major = B^T)
    const float* bias = (const float*)d_in[2];  // [N]
    float* out = (float*)d_out;

    const int xn = in_sizes[0];
    const int wn = in_sizes[1];
    const int N = in_sizes[2];
    const int K = wn / N;
    const int M = xn / K;

    int* amax = (int*)d_ws;                     // [0]=absmax(x) bits, [1]=absmax(w) bits
    char* qx = (char*)d_ws + 1024;
    char* qw = qx + (size_t)M * K;

    const int GAX = 2048, GAW = 256;
    absmax2_kernel<<<GAX + GAW, 256, 0, stream>>>(
        (const float4*)x, xn / 4, (const float4*)w, wn / 4, GAX, amax);

    const int GQX = 4096, GQW = 256;
    quant2_kernel<<<GQX + GQW, 256, 0, stream>>>(
        (const float4*)x, (int4v*)qx, xn / 16,
        (const float4*)w, (int4v*)qw, wn / 16, GQX, amax);

    const int nbx = N / BN;
    gemm_i8_kernel<<<nbx * (M / BM), 256, 0, stream>>>(qx, qw, bias, amax, out, M, N, K, nbx);
}